// Round 1
// baseline (1665.674 us; speedup 1.0000x reference)
//
#include <hip/hip_runtime.h>
#include <hip/hip_bf16.h>

#ifndef MINi
#define MINi(a,b) ((a)<(b)?(a):(b))
#endif

// ---------------------------------------------------------------------------
// Kernel 1: degree count (edges only; self-loop added later as +1)
// ---------------------------------------------------------------------------
__global__ __launch_bounds__(256)
void deg_kernel(const int* __restrict__ ei, int* __restrict__ cnt, int nE)
{
    int e = blockIdx.x * 256 + threadIdx.x;
    if (e >= nE) return;
    int2 p = ((const int2*)ei)[e];   // (src, dst)
    atomicAdd(&cnt[p.y], 1);
}

// ---------------------------------------------------------------------------
// Kernel 2: single-block exclusive scan -> row_start, cursor; also dinv
// ---------------------------------------------------------------------------
__global__ __launch_bounds__(1024)
void scan_kernel(const int* __restrict__ cnt, int* __restrict__ row_start,
                 int* __restrict__ cursor, float* __restrict__ dinv, int n)
{
    __shared__ int lds[1024];
    int t = threadIdx.x;
    int chunk = (n + 1023) >> 10;
    int lo = t * chunk;
    int hi = MINi(lo + chunk, n);
    int s = 0;
    for (int i = lo; i < hi; ++i) s += cnt[i];
    lds[t] = s;
    __syncthreads();
    // inclusive Hillis-Steele scan over 1024 partial sums
    for (int off = 1; off < 1024; off <<= 1) {
        int add = (t >= off) ? lds[t - off] : 0;
        __syncthreads();
        lds[t] += add;
        __syncthreads();
    }
    int run = lds[t] - s;   // exclusive prefix of this thread's chunk
    for (int i = lo; i < hi; ++i) {
        row_start[i] = run;
        cursor[i]    = run;
        dinv[i]      = rsqrtf((float)(cnt[i] + 1));   // +1 self-loop
        run += cnt[i];
    }
    if (t == 0) row_start[n] = lds[1023];
}

// ---------------------------------------------------------------------------
// Kernel 3: CSR fill (src index + precomputed edge norm packed as int2)
// ---------------------------------------------------------------------------
__global__ __launch_bounds__(256)
void fill_kernel(const int* __restrict__ ei, const float* __restrict__ dinv,
                 int* __restrict__ cursor, int2* __restrict__ csr, int nE)
{
    int e = blockIdx.x * 256 + threadIdx.x;
    if (e >= nE) return;
    int2 p = ((const int2*)ei)[e];   // (src, dst)
    int pos = atomicAdd(&cursor[p.y], 1);
    float nw = dinv[p.x] * dinv[p.y];
    csr[pos] = make_int2(p.x, __float_as_int(nw));
}

// ---------------------------------------------------------------------------
// Kernel 4: aggregation  out[b,d,:] = dinv[d]^2 * x[b,d,:] + sum_e nw_e * x[b,src_e,:]
// one wave per (b,d); lane owns 2 features (float2)
// ---------------------------------------------------------------------------
__global__ __launch_bounds__(256)
void agg_kernel(const float* __restrict__ x, float* __restrict__ out,
                const int* __restrict__ row_start, const int2* __restrict__ csr,
                const float* __restrict__ dinv, int n)
{
    int wid  = (blockIdx.x << 2) + (threadIdx.x >> 6);
    int lane = threadIdx.x & 63;
    if (wid >= 2 * n) return;
    int b = (wid >= n) ? 1 : 0;
    int d = wid - b * n;
    const float* xb = x + (size_t)b * n * 128;

    float sd = dinv[d];
    float2 xs = *(const float2*)(xb + (size_t)d * 128 + 2 * lane);
    float ax = sd * sd * xs.x;
    float ay = sd * sd * xs.y;

    int rs = row_start[d], re = row_start[d + 1];
    for (int e = rs; e < re; e += 64) {
        int idx = e + lane;
        int2 pk = csr[idx < re ? idx : re - 1];
        int cnt = MINi(re - e, 64);
        #pragma unroll 4
        for (int i = 0; i < cnt; ++i) {
            int   src = __shfl(pk.x, i);
            float nw  = __shfl(__int_as_float(pk.y), i);
            float2 xv = *(const float2*)(xb + (size_t)src * 128 + 2 * lane);
            ax += nw * xv.x;
            ay += nw * xv.y;
        }
    }
    float2 o; o.x = ax; o.y = ay;
    *(float2*)(out + (size_t)wid * 128 + 2 * lane) = o;
}

// ---------------------------------------------------------------------------
// Kernel 5: row GEMM + bias + relu:  out[r,:] = relu(in[r,:] @ W + b)
// 512 threads, 128-row tile; W (64KB) + x-tile (66KB, pitch 132) in LDS
// thread tile = 4 rows x 8 cols. In-place safe (tile staged before stores).
// ---------------------------------------------------------------------------
__global__ __launch_bounds__(512, 1)
void gemm_kernel(const float* __restrict__ in, const float* __restrict__ W,
                 const float* __restrict__ bias, float* __restrict__ out, int nrows)
{
    __shared__ float wl[128 * 128];
    __shared__ float xl[128 * 132];
    int t  = threadIdx.x;
    int r0 = blockIdx.x * 128;

    // stage W (16384 floats = 4096 float4; 8 per thread)
    {
        const float4* w4  = (const float4*)W;
        float4*       wl4 = (float4*)wl;
        #pragma unroll
        for (int i = 0; i < 8; ++i) wl4[t + i * 512] = w4[t + i * 512];
    }
    // stage x tile (coalesced read, padded LDS rows)
    #pragma unroll
    for (int i = 0; i < 8; ++i) {
        int idx = t + i * 512;          // float4 index in tile
        int r = idx >> 5;               // 32 float4 per row
        int c = idx & 31;
        int gr = r0 + r;
        float4 v = make_float4(0.f, 0.f, 0.f, 0.f);
        if (gr < nrows) v = ((const float4*)in)[(size_t)gr * 32 + c];
        *(float4*)&xl[r * 132 + c * 4] = v;
    }
    __syncthreads();

    int rg = t >> 4, cg = t & 15;
    int rb = rg << 2, cb = cg << 3;
    float acc[4][8];
    #pragma unroll
    for (int j = 0; j < 4; ++j)
        #pragma unroll
        for (int q = 0; q < 8; ++q) acc[j][q] = 0.f;

    for (int k = 0; k < 128; ++k) {
        float xv0 = xl[(rb + 0) * 132 + k];
        float xv1 = xl[(rb + 1) * 132 + k];
        float xv2 = xl[(rb + 2) * 132 + k];
        float xv3 = xl[(rb + 3) * 132 + k];
        float4 wa = *(const float4*)&wl[k * 128 + cb];
        float4 wb = *(const float4*)&wl[k * 128 + cb + 4];
        acc[0][0] += xv0 * wa.x; acc[0][1] += xv0 * wa.y; acc[0][2] += xv0 * wa.z; acc[0][3] += xv0 * wa.w;
        acc[0][4] += xv0 * wb.x; acc[0][5] += xv0 * wb.y; acc[0][6] += xv0 * wb.z; acc[0][7] += xv0 * wb.w;
        acc[1][0] += xv1 * wa.x; acc[1][1] += xv1 * wa.y; acc[1][2] += xv1 * wa.z; acc[1][3] += xv1 * wa.w;
        acc[1][4] += xv1 * wb.x; acc[1][5] += xv1 * wb.y; acc[1][6] += xv1 * wb.z; acc[1][7] += xv1 * wb.w;
        acc[2][0] += xv2 * wa.x; acc[2][1] += xv2 * wa.y; acc[2][2] += xv2 * wa.z; acc[2][3] += xv2 * wa.w;
        acc[2][4] += xv2 * wb.x; acc[2][5] += xv2 * wb.y; acc[2][6] += xv2 * wb.z; acc[2][7] += xv2 * wb.w;
        acc[3][0] += xv3 * wa.x; acc[3][1] += xv3 * wa.y; acc[3][2] += xv3 * wa.z; acc[3][3] += xv3 * wa.w;
        acc[3][4] += xv3 * wb.x; acc[3][5] += xv3 * wb.y; acc[3][6] += xv3 * wb.z; acc[3][7] += xv3 * wb.w;
    }

    float bv[8];
    #pragma unroll
    for (int q = 0; q < 8; ++q) bv[q] = bias[cb + q];

    #pragma unroll
    for (int j = 0; j < 4; ++j) {
        int gr = r0 + rb + j;
        if (gr < nrows) {
            float4 oa, ob;
            oa.x = fmaxf(acc[j][0] + bv[0], 0.f);
            oa.y = fmaxf(acc[j][1] + bv[1], 0.f);
            oa.z = fmaxf(acc[j][2] + bv[2], 0.f);
            oa.w = fmaxf(acc[j][3] + bv[3], 0.f);
            ob.x = fmaxf(acc[j][4] + bv[4], 0.f);
            ob.y = fmaxf(acc[j][5] + bv[5], 0.f);
            ob.z = fmaxf(acc[j][6] + bv[6], 0.f);
            ob.w = fmaxf(acc[j][7] + bv[7], 0.f);
            *(float4*)&out[(size_t)gr * 128 + cb]     = oa;
            *(float4*)&out[(size_t)gr * 128 + cb + 4] = ob;
        }
    }
}

// ---------------------------------------------------------------------------
static inline size_t align_up(size_t x, size_t a) { return (x + a - 1) & ~(a - 1); }

extern "C" void kernel_launch(void* const* d_in, const int* in_sizes, int n_in,
                              void* d_out, int out_size, void* d_ws, size_t ws_size,
                              hipStream_t stream)
{
    const float* xin = (const float*)d_in[0];
    const int*   ei  = (const int*)d_in[1];
    const float* W1  = (const float*)d_in[2];
    const float* b1  = (const float*)d_in[3];
    const float* W2  = (const float*)d_in[4];
    const float* b2  = (const float*)d_in[5];
    const float* W3  = (const float*)d_in[6];
    const float* b3  = (const float*)d_in[7];
    float* out = (float*)d_out;

    const int N = in_sizes[0] / 256;   // 100000 (B=2, F=128)
    const int E = in_sizes[1] / 2;     // 1600000
    const int ROWS = 2 * N;            // B*N

    char* ws = (char*)d_ws;
    size_t off = 0;
    float* X = (float*)(ws + off);          off = align_up(off + (size_t)ROWS * 128 * 4, 256);
    int* cnt = (int*)(ws + off);            off = align_up(off + (size_t)N * 4, 256);
    int* row_start = (int*)(ws + off);      off = align_up(off + (size_t)(N + 1) * 4, 256);
    int* cursor = (int*)(ws + off);         off = align_up(off + (size_t)N * 4, 256);
    float* dinvp = (float*)(ws + off);      off = align_up(off + (size_t)N * 4, 256);
    int2* csr = (int2*)(ws + off);          off = align_up(off + (size_t)E * 8, 256);

    // ---- build CSR (rebuilt every launch; graph-capture safe) ----
    hipMemsetAsync(cnt, 0, (size_t)N * 4, stream);
    deg_kernel<<<(E + 255) / 256, 256, 0, stream>>>(ei, cnt, E);
    scan_kernel<<<1, 1024, 0, stream>>>(cnt, row_start, cursor, dinvp, N);
    fill_kernel<<<(E + 255) / 256, 256, 0, stream>>>(ei, dinvp, cursor, csr, E);

    const int agrid = (2 * N + 3) / 4;          // 4 waves / block, 1 wave per (b,d)
    const int ggrid = (ROWS + 127) / 128;

    // layer 1: agg(xin -> out), gemm(out -> X)
    agg_kernel<<<agrid, 256, 0, stream>>>(xin, out, row_start, csr, dinvp, N);
    gemm_kernel<<<ggrid, 512, 0, stream>>>(out, W1, b1, X, ROWS);
    // layer 2: agg(X -> out), gemm(out -> X)
    agg_kernel<<<agrid, 256, 0, stream>>>(X, out, row_start, csr, dinvp, N);
    gemm_kernel<<<ggrid, 512, 0, stream>>>(out, W2, b2, X, ROWS);
    // layer 3: agg(X -> out), gemm(out -> out, in-place safe)
    agg_kernel<<<agrid, 256, 0, stream>>>(X, out, row_start, csr, dinvp, N);
    gemm_kernel<<<ggrid, 512, 0, stream>>>(out, W3, b3, out, ROWS);
}

// Round 2
// 1411.787 us; speedup vs baseline: 1.1798x; 1.1798x over previous
//
#include <hip/hip_runtime.h>
#include <hip/hip_bf16.h>

#ifndef MINi
#define MINi(a,b) ((a)<(b)?(a):(b))
#endif

// ---------------------------------------------------------------------------
// Kernel 1: degree count (edges only; self-loop added later as +1)
// ---------------------------------------------------------------------------
__global__ __launch_bounds__(256)
void deg_kernel(const int* __restrict__ ei, int* __restrict__ cnt, int nE)
{
    int e = blockIdx.x * 256 + threadIdx.x;
    if (e >= nE) return;
    int2 p = ((const int2*)ei)[e];   // (src, dst)
    atomicAdd(&cnt[p.y], 1);
}

// ---------------------------------------------------------------------------
// Hierarchical scan: (a) per-block partial sums over 1024-elem chunks,
// (b) single-block exclusive scan of the ~98 partials,
// (c) per-block local scan + offset, writing row_start/cursor/dinv.
// ---------------------------------------------------------------------------
__global__ __launch_bounds__(256)
void scan_partials(const int* __restrict__ cnt, int* __restrict__ bsum, int n)
{
    __shared__ int red[4];
    int base = blockIdx.x * 1024;
    int t = threadIdx.x;
    int s = 0;
    #pragma unroll
    for (int i = 0; i < 4; ++i) {
        int idx = base + t * 4 + i;
        if (idx < n) s += cnt[idx];
    }
    #pragma unroll
    for (int off = 1; off < 64; off <<= 1) s += __shfl_xor(s, off);
    if ((t & 63) == 0) red[t >> 6] = s;
    __syncthreads();
    if (t == 0) bsum[blockIdx.x] = red[0] + red[1] + red[2] + red[3];
}

__global__ __launch_bounds__(128)
void scan_bsums(int* __restrict__ bsum, int nb)
{
    __shared__ int lds[128];
    int t = threadIdx.x;
    int v = (t < nb) ? bsum[t] : 0;
    lds[t] = v;
    __syncthreads();
    for (int off = 1; off < 128; off <<= 1) {
        int add = (t >= off) ? lds[t - off] : 0;
        __syncthreads();
        lds[t] += add;
        __syncthreads();
    }
    if (t < nb) bsum[t] = lds[t] - v;   // exclusive
}

__global__ __launch_bounds__(256)
void scan_final(const int* __restrict__ cnt, const int* __restrict__ bsum,
                int* __restrict__ row_start, int* __restrict__ cursor,
                float* __restrict__ dinv, int n, int nE)
{
    __shared__ int tsum[256];
    int base = blockIdx.x * 1024;
    int t = threadIdx.x;
    int c[4]; int s = 0;
    #pragma unroll
    for (int i = 0; i < 4; ++i) {
        int idx = base + t * 4 + i;
        c[i] = (idx < n) ? cnt[idx] : 0;
        s += c[i];
    }
    tsum[t] = s;
    __syncthreads();
    for (int off = 1; off < 256; off <<= 1) {
        int add = (t >= off) ? tsum[t - off] : 0;
        __syncthreads();
        tsum[t] += add;
        __syncthreads();
    }
    int run = bsum[blockIdx.x] + tsum[t] - s;   // exclusive prefix of this thread
    #pragma unroll
    for (int i = 0; i < 4; ++i) {
        int idx = base + t * 4 + i;
        if (idx < n) {
            row_start[idx] = run;
            cursor[idx]    = run;
            dinv[idx]      = rsqrtf((float)(c[i] + 1));   // +1 self-loop
            run += c[i];
        }
    }
    if (blockIdx.x == 0 && t == 0) row_start[n] = nE;
}

// ---------------------------------------------------------------------------
// Kernel 3: CSR fill (src index + precomputed edge norm packed as int2)
// ---------------------------------------------------------------------------
__global__ __launch_bounds__(256)
void fill_kernel(const int* __restrict__ ei, const float* __restrict__ dinv,
                 int* __restrict__ cursor, int2* __restrict__ csr, int nE)
{
    int e = blockIdx.x * 256 + threadIdx.x;
    if (e >= nE) return;
    int2 p = ((const int2*)ei)[e];   // (src, dst)
    int pos = atomicAdd(&cursor[p.y], 1);
    float nw = dinv[p.x] * dinv[p.y];
    csr[pos] = make_int2(p.x, __float_as_int(nw));
}

// ---------------------------------------------------------------------------
// Kernel 4: aggregation, both batches in one wave.
// lane 0-31: batch 0, features 4*(lane&31)..+3 (float4)
// lane 32-63: batch 1, same features.
// All 64 lanes hold one csr edge each per 64-chunk; broadcast via shfl.
// ---------------------------------------------------------------------------
__global__ __launch_bounds__(256)
void agg_kernel(const float* __restrict__ x, float* __restrict__ out,
                const int* __restrict__ row_start, const int2* __restrict__ csr,
                const float* __restrict__ dinv, int n)
{
    int d = (blockIdx.x << 2) + (threadIdx.x >> 6);
    if (d >= n) return;
    int lane = threadIdx.x & 63;
    int half = lane >> 5;                 // batch index
    int f4   = (lane & 31) << 2;          // feature offset
    const float* xb = x + (size_t)half * n * 128 + f4;

    float sd = dinv[d];
    float s2 = sd * sd;
    float4 acc = *(const float4*)(xb + (size_t)d * 128);
    acc.x *= s2; acc.y *= s2; acc.z *= s2; acc.w *= s2;

    int rs = row_start[d], re = row_start[d + 1];
    for (int e = rs; e < re; e += 64) {
        int idx = e + lane;
        int2 pk = csr[idx < re ? idx : re - 1];
        int cnt = MINi(re - e, 64);
        #pragma unroll 4
        for (int i = 0; i < cnt; ++i) {
            int   src = __shfl(pk.x, i);
            float nw  = __shfl(__int_as_float(pk.y), i);
            float4 xv = *(const float4*)(xb + (size_t)src * 128);
            acc.x += nw * xv.x; acc.y += nw * xv.y;
            acc.z += nw * xv.z; acc.w += nw * xv.w;
        }
    }
    *(float4*)(out + (size_t)(half * n + d) * 128 + f4) = acc;
}

// ---------------------------------------------------------------------------
// Kernel 5: row GEMM + bias + relu:  out[r,:] = relu(in[r,:] @ W + b)
// ---------------------------------------------------------------------------
__global__ __launch_bounds__(512, 1)
void gemm_kernel(const float* __restrict__ in, const float* __restrict__ W,
                 const float* __restrict__ bias, float* __restrict__ out, int nrows)
{
    __shared__ float wl[128 * 128];
    __shared__ float xl[128 * 132];
    int t  = threadIdx.x;
    int r0 = blockIdx.x * 128;

    {
        const float4* w4  = (const float4*)W;
        float4*       wl4 = (float4*)wl;
        #pragma unroll
        for (int i = 0; i < 8; ++i) wl4[t + i * 512] = w4[t + i * 512];
    }
    #pragma unroll
    for (int i = 0; i < 8; ++i) {
        int idx = t + i * 512;
        int r = idx >> 5;
        int c = idx & 31;
        int gr = r0 + r;
        float4 v = make_float4(0.f, 0.f, 0.f, 0.f);
        if (gr < nrows) v = ((const float4*)in)[(size_t)gr * 32 + c];
        *(float4*)&xl[r * 132 + c * 4] = v;
    }
    __syncthreads();

    int rg = t >> 4, cg = t & 15;
    int rb = rg << 2, cb = cg << 3;
    float acc[4][8];
    #pragma unroll
    for (int j = 0; j < 4; ++j)
        #pragma unroll
        for (int q = 0; q < 8; ++q) acc[j][q] = 0.f;

    for (int k = 0; k < 128; ++k) {
        float xv0 = xl[(rb + 0) * 132 + k];
        float xv1 = xl[(rb + 1) * 132 + k];
        float xv2 = xl[(rb + 2) * 132 + k];
        float xv3 = xl[(rb + 3) * 132 + k];
        float4 wa = *(const float4*)&wl[k * 128 + cb];
        float4 wb = *(const float4*)&wl[k * 128 + cb + 4];
        acc[0][0] += xv0 * wa.x; acc[0][1] += xv0 * wa.y; acc[0][2] += xv0 * wa.z; acc[0][3] += xv0 * wa.w;
        acc[0][4] += xv0 * wb.x; acc[0][5] += xv0 * wb.y; acc[0][6] += xv0 * wb.z; acc[0][7] += xv0 * wb.w;
        acc[1][0] += xv1 * wa.x; acc[1][1] += xv1 * wa.y; acc[1][2] += xv1 * wa.z; acc[1][3] += xv1 * wa.w;
        acc[1][4] += xv1 * wb.x; acc[1][5] += xv1 * wb.y; acc[1][6] += xv1 * wb.z; acc[1][7] += xv1 * wb.w;
        acc[2][0] += xv2 * wa.x; acc[2][1] += xv2 * wa.y; acc[2][2] += xv2 * wa.z; acc[2][3] += xv2 * wa.w;
        acc[2][4] += xv2 * wb.x; acc[2][5] += xv2 * wb.y; acc[2][6] += xv2 * wb.z; acc[2][7] += xv2 * wb.w;
        acc[3][0] += xv3 * wa.x; acc[3][1] += xv3 * wa.y; acc[3][2] += xv3 * wa.z; acc[3][3] += xv3 * wa.w;
        acc[3][4] += xv3 * wb.x; acc[3][5] += xv3 * wb.y; acc[3][6] += xv3 * wb.z; acc[3][7] += xv3 * wb.w;
    }

    float bv[8];
    #pragma unroll
    for (int q = 0; q < 8; ++q) bv[q] = bias[cb + q];

    #pragma unroll
    for (int j = 0; j < 4; ++j) {
        int gr = r0 + rb + j;
        if (gr < nrows) {
            float4 oa, ob;
            oa.x = fmaxf(acc[j][0] + bv[0], 0.f);
            oa.y = fmaxf(acc[j][1] + bv[1], 0.f);
            oa.z = fmaxf(acc[j][2] + bv[2], 0.f);
            oa.w = fmaxf(acc[j][3] + bv[3], 0.f);
            ob.x = fmaxf(acc[j][4] + bv[4], 0.f);
            ob.y = fmaxf(acc[j][5] + bv[5], 0.f);
            ob.z = fmaxf(acc[j][6] + bv[6], 0.f);
            ob.w = fmaxf(acc[j][7] + bv[7], 0.f);
            *(float4*)&out[(size_t)gr * 128 + cb]     = oa;
            *(float4*)&out[(size_t)gr * 128 + cb + 4] = ob;
        }
    }
}

// ---------------------------------------------------------------------------
static inline size_t align_up(size_t x, size_t a) { return (x + a - 1) & ~(a - 1); }

extern "C" void kernel_launch(void* const* d_in, const int* in_sizes, int n_in,
                              void* d_out, int out_size, void* d_ws, size_t ws_size,
                              hipStream_t stream)
{
    const float* xin = (const float*)d_in[0];
    const int*   ei  = (const int*)d_in[1];
    const float* W1  = (const float*)d_in[2];
    const float* b1  = (const float*)d_in[3];
    const float* W2  = (const float*)d_in[4];
    const float* b2  = (const float*)d_in[5];
    const float* W3  = (const float*)d_in[6];
    const float* b3  = (const float*)d_in[7];
    float* out = (float*)d_out;

    const int N = in_sizes[0] / 256;   // 100000 (B=2, F=128)
    const int E = in_sizes[1] / 2;     // 1600000
    const int ROWS = 2 * N;            // B*N

    char* ws = (char*)d_ws;
    size_t off = 0;
    float* X = (float*)(ws + off);          off = align_up(off + (size_t)ROWS * 128 * 4, 256);
    int* cnt = (int*)(ws + off);            off = align_up(off + (size_t)N * 4, 256);
    int* row_start = (int*)(ws + off);      off = align_up(off + (size_t)(N + 1) * 4, 256);
    int* cursor = (int*)(ws + off);         off = align_up(off + (size_t)N * 4, 256);
    float* dinvp = (float*)(ws + off);      off = align_up(off + (size_t)N * 4, 256);
    int* bsum = (int*)(ws + off);           off = align_up(off + 1024 * 4, 256);
    int2* csr = (int2*)(ws + off);          off = align_up(off + (size_t)E * 8, 256);

    const int nb = (N + 1023) / 1024;      // 98 scan blocks

    // ---- build CSR (rebuilt every launch; graph-capture safe) ----
    hipMemsetAsync(cnt, 0, (size_t)N * 4, stream);
    deg_kernel<<<(E + 255) / 256, 256, 0, stream>>>(ei, cnt, E);
    scan_partials<<<nb, 256, 0, stream>>>(cnt, bsum, N);
    scan_bsums<<<1, 128, 0, stream>>>(bsum, nb);
    scan_final<<<nb, 256, 0, stream>>>(cnt, bsum, row_start, cursor, dinvp, N, E);
    fill_kernel<<<(E + 255) / 256, 256, 0, stream>>>(ei, dinvp, cursor, csr, E);

    const int agrid = (N + 3) / 4;          // 4 waves / block, 1 wave per node (both batches)
    const int ggrid = (ROWS + 127) / 128;

    // layer 1: agg(xin -> out), gemm(out -> X)
    agg_kernel<<<agrid, 256, 0, stream>>>(xin, out, row_start, csr, dinvp, N);
    gemm_kernel<<<ggrid, 512, 0, stream>>>(out, W1, b1, X, ROWS);
    // layer 2: agg(X -> out), gemm(out -> X)
    agg_kernel<<<agrid, 256, 0, stream>>>(X, out, row_start, csr, dinvp, N);
    gemm_kernel<<<ggrid, 512, 0, stream>>>(out, W2, b2, X, ROWS);
    // layer 3: agg(X -> out), gemm(out -> out, in-place safe)
    agg_kernel<<<agrid, 256, 0, stream>>>(X, out, row_start, csr, dinvp, N);
    gemm_kernel<<<ggrid, 512, 0, stream>>>(out, W3, b3, out, ROWS);
}

// Round 3
// 1109.966 us; speedup vs baseline: 1.5007x; 1.2719x over previous
//
#include <hip/hip_runtime.h>
#include <hip/hip_bf16.h>
#include <hip/hip_fp16.h>

#ifndef MINi
#define MINi(a,b) ((a)<(b)?(a):(b))
#endif

// ---------------------------------------------------------------------------
// Kernel 0: fp32 -> fp16 convert (4 elems/thread)
// ---------------------------------------------------------------------------
__global__ __launch_bounds__(256)
void cvt_kernel(const float* __restrict__ in, __half* __restrict__ out, int n4)
{
    int i = blockIdx.x * 256 + threadIdx.x;
    if (i >= n4) return;
    float4 v = ((const float4*)in)[i];
    float2 st;
    ((__half2*)&st)[0] = __floats2half2_rn(v.x, v.y);
    ((__half2*)&st)[1] = __floats2half2_rn(v.z, v.w);
    ((float2*)out)[i] = st;
}

// ---------------------------------------------------------------------------
// Kernel 1: degree count (edges only; self-loop added later as +1)
// ---------------------------------------------------------------------------
__global__ __launch_bounds__(256)
void deg_kernel(const int* __restrict__ ei, int* __restrict__ cnt, int nE)
{
    int e = blockIdx.x * 256 + threadIdx.x;
    if (e >= nE) return;
    int2 p = ((const int2*)ei)[e];   // (src, dst)
    atomicAdd(&cnt[p.y], 1);
}

// ---------------------------------------------------------------------------
// Hierarchical scan
// ---------------------------------------------------------------------------
__global__ __launch_bounds__(256)
void scan_partials(const int* __restrict__ cnt, int* __restrict__ bsum, int n)
{
    __shared__ int red[4];
    int base = blockIdx.x * 1024;
    int t = threadIdx.x;
    int s = 0;
    #pragma unroll
    for (int i = 0; i < 4; ++i) {
        int idx = base + t * 4 + i;
        if (idx < n) s += cnt[idx];
    }
    #pragma unroll
    for (int off = 1; off < 64; off <<= 1) s += __shfl_xor(s, off);
    if ((t & 63) == 0) red[t >> 6] = s;
    __syncthreads();
    if (t == 0) bsum[blockIdx.x] = red[0] + red[1] + red[2] + red[3];
}

__global__ __launch_bounds__(128)
void scan_bsums(int* __restrict__ bsum, int nb)
{
    __shared__ int lds[128];
    int t = threadIdx.x;
    int v = (t < nb) ? bsum[t] : 0;
    lds[t] = v;
    __syncthreads();
    for (int off = 1; off < 128; off <<= 1) {
        int add = (t >= off) ? lds[t - off] : 0;
        __syncthreads();
        lds[t] += add;
        __syncthreads();
    }
    if (t < nb) bsum[t] = lds[t] - v;   // exclusive
}

__global__ __launch_bounds__(256)
void scan_final(const int* __restrict__ cnt, const int* __restrict__ bsum,
                int* __restrict__ row_start, int* __restrict__ cursor,
                float* __restrict__ dinv, int n, int nE)
{
    __shared__ int tsum[256];
    int base = blockIdx.x * 1024;
    int t = threadIdx.x;
    int c[4]; int s = 0;
    #pragma unroll
    for (int i = 0; i < 4; ++i) {
        int idx = base + t * 4 + i;
        c[i] = (idx < n) ? cnt[idx] : 0;
        s += c[i];
    }
    tsum[t] = s;
    __syncthreads();
    for (int off = 1; off < 256; off <<= 1) {
        int add = (t >= off) ? tsum[t - off] : 0;
        __syncthreads();
        tsum[t] += add;
        __syncthreads();
    }
    int run = bsum[blockIdx.x] + tsum[t] - s;
    #pragma unroll
    for (int i = 0; i < 4; ++i) {
        int idx = base + t * 4 + i;
        if (idx < n) {
            row_start[idx] = run;
            cursor[idx]    = run;
            dinv[idx]      = rsqrtf((float)(c[i] + 1));
            run += c[i];
        }
    }
    if (blockIdx.x == 0 && t == 0) row_start[n] = nE;
}

// ---------------------------------------------------------------------------
// Kernel 3: CSR fill
// ---------------------------------------------------------------------------
__global__ __launch_bounds__(256)
void fill_kernel(const int* __restrict__ ei, const float* __restrict__ dinv,
                 int* __restrict__ cursor, int2* __restrict__ csr, int nE)
{
    int e = blockIdx.x * 256 + threadIdx.x;
    if (e >= nE) return;
    int2 p = ((const int2*)ei)[e];
    int pos = atomicAdd(&cursor[p.y], 1);
    float nw = dinv[p.x] * dinv[p.y];
    csr[pos] = make_int2(p.x, __float_as_int(nw));
}

// ---------------------------------------------------------------------------
// Kernel 4: aggregation over fp16 x, fp32 accumulate, fp32 out.
// lane 0-31: batch 0, lane 32-63: batch 1; each lane owns 4 features (8 B).
// ---------------------------------------------------------------------------
__global__ __launch_bounds__(256)
void agg_kernel(const __half* __restrict__ x, float* __restrict__ out,
                const int* __restrict__ row_start, const int2* __restrict__ csr,
                const float* __restrict__ dinv, int n)
{
    int d = (blockIdx.x << 2) + (threadIdx.x >> 6);
    if (d >= n) return;
    int lane = threadIdx.x & 63;
    int hb   = lane >> 5;                 // batch index
    int fo   = (lane & 31) << 2;          // feature offset (4 feats)
    const __half* xb = x + (size_t)hb * n * 128 + fo;

    float sd = dinv[d], s2 = sd * sd;
    float2 raw = *(const float2*)(xb + (size_t)d * 128);
    float2 f0 = __half22float2(((__half2*)&raw)[0]);
    float2 f1 = __half22float2(((__half2*)&raw)[1]);
    float a0 = s2 * f0.x, a1 = s2 * f0.y, a2 = s2 * f1.x, a3 = s2 * f1.y;

    int rs = row_start[d], re = row_start[d + 1];
    for (int e = rs; e < re; e += 64) {
        int idx = e + lane;
        int2 pk = csr[idx < re ? idx : re - 1];
        int cnt = MINi(re - e, 64);
        #pragma unroll 4
        for (int i = 0; i < cnt; ++i) {
            int   src = __shfl(pk.x, i);
            float nw  = __shfl(__int_as_float(pk.y), i);
            float2 rv = *(const float2*)(xb + (size_t)src * 128);
            float2 u0 = __half22float2(((__half2*)&rv)[0]);
            float2 u1 = __half22float2(((__half2*)&rv)[1]);
            a0 += nw * u0.x; a1 += nw * u0.y; a2 += nw * u1.x; a3 += nw * u1.y;
        }
    }
    *(float4*)(out + (size_t)(hb * n + d) * 128 + fo) = make_float4(a0, a1, a2, a3);
}

// ---------------------------------------------------------------------------
// Kernel 5: row GEMM + bias + relu. HALF_OUT: store fp16 (for next agg).
// ---------------------------------------------------------------------------
template<bool HALF_OUT>
__global__ __launch_bounds__(512, 1)
void gemm_kernel(const float* __restrict__ in, const float* __restrict__ W,
                 const float* __restrict__ bias, void* __restrict__ outp, int nrows)
{
    __shared__ float wl[128 * 128];
    __shared__ float xl[128 * 132];
    int t  = threadIdx.x;
    int r0 = blockIdx.x * 128;

    {
        const float4* w4  = (const float4*)W;
        float4*       wl4 = (float4*)wl;
        #pragma unroll
        for (int i = 0; i < 8; ++i) wl4[t + i * 512] = w4[t + i * 512];
    }
    #pragma unroll
    for (int i = 0; i < 8; ++i) {
        int idx = t + i * 512;
        int r = idx >> 5;
        int c = idx & 31;
        int gr = r0 + r;
        float4 v = make_float4(0.f, 0.f, 0.f, 0.f);
        if (gr < nrows) v = ((const float4*)in)[(size_t)gr * 32 + c];
        *(float4*)&xl[r * 132 + c * 4] = v;
    }
    __syncthreads();

    int rg = t >> 4, cg = t & 15;
    int rb = rg << 2, cb = cg << 3;
    float acc[4][8];
    #pragma unroll
    for (int j = 0; j < 4; ++j)
        #pragma unroll
        for (int q = 0; q < 8; ++q) acc[j][q] = 0.f;

    for (int k = 0; k < 128; ++k) {
        float xv0 = xl[(rb + 0) * 132 + k];
        float xv1 = xl[(rb + 1) * 132 + k];
        float xv2 = xl[(rb + 2) * 132 + k];
        float xv3 = xl[(rb + 3) * 132 + k];
        float4 wa = *(const float4*)&wl[k * 128 + cb];
        float4 wb = *(const float4*)&wl[k * 128 + cb + 4];
        acc[0][0] += xv0 * wa.x; acc[0][1] += xv0 * wa.y; acc[0][2] += xv0 * wa.z; acc[0][3] += xv0 * wa.w;
        acc[0][4] += xv0 * wb.x; acc[0][5] += xv0 * wb.y; acc[0][6] += xv0 * wb.z; acc[0][7] += xv0 * wb.w;
        acc[1][0] += xv1 * wa.x; acc[1][1] += xv1 * wa.y; acc[1][2] += xv1 * wa.z; acc[1][3] += xv1 * wa.w;
        acc[1][4] += xv1 * wb.x; acc[1][5] += xv1 * wb.y; acc[1][6] += xv1 * wb.z; acc[1][7] += xv1 * wb.w;
        acc[2][0] += xv2 * wa.x; acc[2][1] += xv2 * wa.y; acc[2][2] += xv2 * wa.z; acc[2][3] += xv2 * wa.w;
        acc[2][4] += xv2 * wb.x; acc[2][5] += xv2 * wb.y; acc[2][6] += xv2 * wb.z; acc[2][7] += xv2 * wb.w;
        acc[3][0] += xv3 * wa.x; acc[3][1] += xv3 * wa.y; acc[3][2] += xv3 * wa.z; acc[3][3] += xv3 * wa.w;
        acc[3][4] += xv3 * wb.x; acc[3][5] += xv3 * wb.y; acc[3][6] += xv3 * wb.z; acc[3][7] += xv3 * wb.w;
    }

    float bv[8];
    #pragma unroll
    for (int q = 0; q < 8; ++q) bv[q] = bias[cb + q];

    #pragma unroll
    for (int j = 0; j < 4; ++j) {
        int gr = r0 + rb + j;
        if (gr < nrows) {
            float v[8];
            #pragma unroll
            for (int q = 0; q < 8; ++q) v[q] = fmaxf(acc[j][q] + bv[q], 0.f);
            if constexpr (HALF_OUT) {
                __half* o = (__half*)outp;
                float4 st;
                ((__half2*)&st)[0] = __floats2half2_rn(v[0], v[1]);
                ((__half2*)&st)[1] = __floats2half2_rn(v[2], v[3]);
                ((__half2*)&st)[2] = __floats2half2_rn(v[4], v[5]);
                ((__half2*)&st)[3] = __floats2half2_rn(v[6], v[7]);
                *(float4*)&o[(size_t)gr * 128 + cb] = st;   // 8 halfs = 16 B
            } else {
                float* o = (float*)outp;
                *(float4*)&o[(size_t)gr * 128 + cb]     = make_float4(v[0], v[1], v[2], v[3]);
                *(float4*)&o[(size_t)gr * 128 + cb + 4] = make_float4(v[4], v[5], v[6], v[7]);
            }
        }
    }
}

// ---------------------------------------------------------------------------
static inline size_t align_up(size_t x, size_t a) { return (x + a - 1) & ~(a - 1); }

extern "C" void kernel_launch(void* const* d_in, const int* in_sizes, int n_in,
                              void* d_out, int out_size, void* d_ws, size_t ws_size,
                              hipStream_t stream)
{
    const float* xin = (const float*)d_in[0];
    const int*   ei  = (const int*)d_in[1];
    const float* W1  = (const float*)d_in[2];
    const float* b1  = (const float*)d_in[3];
    const float* W2  = (const float*)d_in[4];
    const float* b2  = (const float*)d_in[5];
    const float* W3  = (const float*)d_in[6];
    const float* b3  = (const float*)d_in[7];
    float* out = (float*)d_out;

    const int N = in_sizes[0] / 256;   // 100000
    const int E = in_sizes[1] / 2;     // 1600000
    const int ROWS = 2 * N;

    char* ws = (char*)d_ws;
    size_t off = 0;
    __half* Xh = (__half*)(ws + off);       off = align_up(off + (size_t)ROWS * 128 * 2, 256);
    int* cnt = (int*)(ws + off);            off = align_up(off + (size_t)N * 4, 256);
    int* row_start = (int*)(ws + off);      off = align_up(off + (size_t)(N + 1) * 4, 256);
    int* cursor = (int*)(ws + off);         off = align_up(off + (size_t)N * 4, 256);
    float* dinvp = (float*)(ws + off);      off = align_up(off + (size_t)N * 4, 256);
    int* bsum = (int*)(ws + off);           off = align_up(off + 1024 * 4, 256);
    int2* csr = (int2*)(ws + off);          off = align_up(off + (size_t)E * 8, 256);

    const int nb = (N + 1023) / 1024;

    // ---- input -> fp16 ----
    const int n4 = ROWS * 32;   // float4 count
    cvt_kernel<<<(n4 + 255) / 256, 256, 0, stream>>>(xin, Xh, n4);

    // ---- build CSR ----
    hipMemsetAsync(cnt, 0, (size_t)N * 4, stream);
    deg_kernel<<<(E + 255) / 256, 256, 0, stream>>>(ei, cnt, E);
    scan_partials<<<nb, 256, 0, stream>>>(cnt, bsum, N);
    scan_bsums<<<1, 128, 0, stream>>>(bsum, nb);
    scan_final<<<nb, 256, 0, stream>>>(cnt, bsum, row_start, cursor, dinvp, N, E);
    fill_kernel<<<(E + 255) / 256, 256, 0, stream>>>(ei, dinvp, cursor, csr, E);

    const int agrid = (N + 3) / 4;
    const int ggrid = (ROWS + 127) / 128;

    // layer 1
    agg_kernel<<<agrid, 256, 0, stream>>>(Xh, out, row_start, csr, dinvp, N);
    gemm_kernel<true><<<ggrid, 512, 0, stream>>>(out, W1, b1, Xh, ROWS);
    // layer 2
    agg_kernel<<<agrid, 256, 0, stream>>>(Xh, out, row_start, csr, dinvp, N);
    gemm_kernel<true><<<ggrid, 512, 0, stream>>>(out, W2, b2, Xh, ROWS);
    // layer 3
    agg_kernel<<<agrid, 256, 0, stream>>>(Xh, out, row_start, csr, dinvp, N);
    gemm_kernel<false><<<ggrid, 512, 0, stream>>>(out, W3, b3, out, ROWS);
}

// Round 4
// 860.337 us; speedup vs baseline: 1.9361x; 1.2902x over previous
//
#include <hip/hip_runtime.h>
#include <hip/hip_bf16.h>
#include <hip/hip_fp16.h>

#ifndef MINi
#define MINi(a,b) ((a)<(b)?(a):(b))
#endif

typedef _Float16 f16x8 __attribute__((ext_vector_type(8)));
typedef _Float16 f16x4 __attribute__((ext_vector_type(4)));
typedef float    f32x4 __attribute__((ext_vector_type(4)));

// ---------------------------------------------------------------------------
// Kernel 0: fp32 -> fp16 convert (4 elems/thread)
// ---------------------------------------------------------------------------
__global__ __launch_bounds__(256)
void cvt_kernel(const float* __restrict__ in, _Float16* __restrict__ out, int n4)
{
    int i = blockIdx.x * 256 + threadIdx.x;
    if (i >= n4) return;
    float4 v = ((const float4*)in)[i];
    f16x4 st = {(_Float16)v.x, (_Float16)v.y, (_Float16)v.z, (_Float16)v.w};
    ((f16x4*)out)[i] = st;
}

// ---------------------------------------------------------------------------
// Kernel 0b: W[k][col] fp32 -> Wt[col][k] fp16 (128x128)
// ---------------------------------------------------------------------------
__global__ __launch_bounds__(256)
void wt_kernel(const float* __restrict__ W, _Float16* __restrict__ Wt)
{
    int idx = blockIdx.x * 256 + threadIdx.x;   // 0..16383
    int k = idx >> 7, col = idx & 127;
    Wt[col * 128 + k] = (_Float16)W[idx];       // read coalesced, write strided
}

// ---------------------------------------------------------------------------
// Kernel 1: degree count
// ---------------------------------------------------------------------------
__global__ __launch_bounds__(256)
void deg_kernel(const int* __restrict__ ei, int* __restrict__ cnt, int nE)
{
    int e = blockIdx.x * 256 + threadIdx.x;
    if (e >= nE) return;
    int2 p = ((const int2*)ei)[e];   // (src, dst)
    atomicAdd(&cnt[p.y], 1);
}

// ---------------------------------------------------------------------------
// Hierarchical scan
// ---------------------------------------------------------------------------
__global__ __launch_bounds__(256)
void scan_partials(const int* __restrict__ cnt, int* __restrict__ bsum, int n)
{
    __shared__ int red[4];
    int base = blockIdx.x * 1024;
    int t = threadIdx.x;
    int s = 0;
    #pragma unroll
    for (int i = 0; i < 4; ++i) {
        int idx = base + t * 4 + i;
        if (idx < n) s += cnt[idx];
    }
    #pragma unroll
    for (int off = 1; off < 64; off <<= 1) s += __shfl_xor(s, off);
    if ((t & 63) == 0) red[t >> 6] = s;
    __syncthreads();
    if (t == 0) bsum[blockIdx.x] = red[0] + red[1] + red[2] + red[3];
}

__global__ __launch_bounds__(128)
void scan_bsums(int* __restrict__ bsum, int nb)
{
    __shared__ int lds[128];
    int t = threadIdx.x;
    int v = (t < nb) ? bsum[t] : 0;
    lds[t] = v;
    __syncthreads();
    for (int off = 1; off < 128; off <<= 1) {
        int add = (t >= off) ? lds[t - off] : 0;
        __syncthreads();
        lds[t] += add;
        __syncthreads();
    }
    if (t < nb) bsum[t] = lds[t] - v;   // exclusive
}

__global__ __launch_bounds__(256)
void scan_final(const int* __restrict__ cnt, const int* __restrict__ bsum,
                int* __restrict__ row_start, int* __restrict__ cursor,
                float* __restrict__ dinv, int n, int nE)
{
    __shared__ int tsum[256];
    int base = blockIdx.x * 1024;
    int t = threadIdx.x;
    int c[4]; int s = 0;
    #pragma unroll
    for (int i = 0; i < 4; ++i) {
        int idx = base + t * 4 + i;
        c[i] = (idx < n) ? cnt[idx] : 0;
        s += c[i];
    }
    tsum[t] = s;
    __syncthreads();
    for (int off = 1; off < 256; off <<= 1) {
        int add = (t >= off) ? tsum[t - off] : 0;
        __syncthreads();
        tsum[t] += add;
        __syncthreads();
    }
    int run = bsum[blockIdx.x] + tsum[t] - s;
    #pragma unroll
    for (int i = 0; i < 4; ++i) {
        int idx = base + t * 4 + i;
        if (idx < n) {
            row_start[idx] = run;
            cursor[idx]    = run;
            dinv[idx]      = rsqrtf((float)(c[i] + 1));
            run += c[i];
        }
    }
    if (blockIdx.x == 0 && t == 0) row_start[n] = nE;
}

// ---------------------------------------------------------------------------
// Kernel 3: CSR fill
// ---------------------------------------------------------------------------
__global__ __launch_bounds__(256)
void fill_kernel(const int* __restrict__ ei, const float* __restrict__ dinv,
                 int* __restrict__ cursor, int2* __restrict__ csr, int nE)
{
    int e = blockIdx.x * 256 + threadIdx.x;
    if (e >= nE) return;
    int2 p = ((const int2*)ei)[e];
    int pos = atomicAdd(&cursor[p.y], 1);
    float nw = dinv[p.x] * dinv[p.y];
    csr[pos] = make_int2(p.x, __float_as_int(nw));
}

// ---------------------------------------------------------------------------
// Kernel 4: aggregation fp16 in, fp32 accumulate, fp16 out.
// lane 0-31: batch 0, lane 32-63: batch 1; each lane owns 4 features (8 B).
// ---------------------------------------------------------------------------
__global__ __launch_bounds__(256)
void agg_kernel(const _Float16* __restrict__ x, _Float16* __restrict__ out,
                const int* __restrict__ row_start, const int2* __restrict__ csr,
                const float* __restrict__ dinv, int n)
{
    int d = (blockIdx.x << 2) + (threadIdx.x >> 6);
    if (d >= n) return;
    int lane = threadIdx.x & 63;
    int hb   = lane >> 5;                 // batch index
    int fo   = (lane & 31) << 2;          // feature offset (4 feats)
    const _Float16* xb = x + (size_t)hb * n * 128 + fo;

    float sd = dinv[d], s2 = sd * sd;
    f16x4 xs = *(const f16x4*)(xb + (size_t)d * 128);
    float a0 = s2 * (float)xs[0], a1 = s2 * (float)xs[1];
    float a2 = s2 * (float)xs[2], a3 = s2 * (float)xs[3];

    int rs = row_start[d], re = row_start[d + 1];
    for (int e = rs; e < re; e += 64) {
        int idx = e + lane;
        int2 pk = csr[idx < re ? idx : re - 1];
        int cnt = MINi(re - e, 64);
        #pragma unroll 4
        for (int i = 0; i < cnt; ++i) {
            int   src = __shfl(pk.x, i);
            float nw  = __shfl(__int_as_float(pk.y), i);
            f16x4 rv = *(const f16x4*)(xb + (size_t)src * 128);
            a0 += nw * (float)rv[0]; a1 += nw * (float)rv[1];
            a2 += nw * (float)rv[2]; a3 += nw * (float)rv[3];
        }
    }
    f16x4 st = {(_Float16)a0, (_Float16)a1, (_Float16)a2, (_Float16)a3};
    *(f16x4*)(out + (size_t)(hb * n + d) * 128 + fo) = st;
}

// ---------------------------------------------------------------------------
// Kernel 5: MFMA GEMM + bias + relu.  out[r,:] = relu(A[r,:] @ W + b)
// A fp16 [nrows][128]; Wt fp16 [col][k] (W transposed); 256 thr = 4 waves.
// Block: 64 rows x 128 cols; wave wv: all 64 rows x cols [wv*32, wv*32+32).
// Frags: lane l: lr=l&15 (M/N idx), lk=l>>4 (k-slice); k = lk*8+j contiguous.
// C (m89): col=l&15, row=(l>>4)*4+reg.  nrows must be divisible by 64.
// ---------------------------------------------------------------------------
template<bool HALF_OUT>
__global__ __launch_bounds__(256)
void gemm_mfma(const _Float16* __restrict__ A, const _Float16* __restrict__ Wt,
               const float* __restrict__ bias, void* __restrict__ outp, int nrows)
{
    int t  = threadIdx.x;
    int wv = t >> 6;
    int l  = t & 63;
    int lr = l & 15;
    int lk = l >> 4;
    size_t r0 = (size_t)blockIdx.x * 64;
    int c0 = wv * 32;

    // preload B-frags from Wt (32KB, L1/L2-resident): frag(ct,ks)
    f16x8 bf[2][4];
    #pragma unroll
    for (int ct = 0; ct < 2; ++ct)
        #pragma unroll
        for (int ks = 0; ks < 4; ++ks)
            bf[ct][ks] = *(const f16x8*)(Wt + (c0 + ct * 16 + lr) * 128 + ks * 32 + lk * 8);

    f32x4 acc[4][2];
    #pragma unroll
    for (int rt = 0; rt < 4; ++rt) {
        acc[rt][0] = (f32x4){0.f, 0.f, 0.f, 0.f};
        acc[rt][1] = (f32x4){0.f, 0.f, 0.f, 0.f};
    }

    #pragma unroll
    for (int rt = 0; rt < 4; ++rt) {
        #pragma unroll
        for (int ks = 0; ks < 4; ++ks) {
            f16x8 af = *(const f16x8*)(A + (r0 + rt * 16 + lr) * 128 + ks * 32 + lk * 8);
            acc[rt][0] = __builtin_amdgcn_mfma_f32_16x16x32_f16(af, bf[0][ks], acc[rt][0], 0, 0, 0);
            acc[rt][1] = __builtin_amdgcn_mfma_f32_16x16x32_f16(af, bf[1][ks], acc[rt][1], 0, 0, 0);
        }
    }

    float bc0 = bias[c0 + lr];
    float bc1 = bias[c0 + 16 + lr];
    #pragma unroll
    for (int rt = 0; rt < 4; ++rt) {
        #pragma unroll
        for (int ct = 0; ct < 2; ++ct) {
            float bc = ct ? bc1 : bc0;
            int col = c0 + ct * 16 + lr;
            #pragma unroll
            for (int r = 0; r < 4; ++r) {
                float v = fmaxf(acc[rt][ct][r] + bc, 0.f);
                size_t row = r0 + rt * 16 + lk * 4 + r;
                if constexpr (HALF_OUT)
                    ((_Float16*)outp)[row * 128 + col] = (_Float16)v;
                else
                    ((float*)outp)[row * 128 + col] = v;
            }
        }
    }
}

// ---------------------------------------------------------------------------
static inline size_t align_up(size_t x, size_t a) { return (x + a - 1) & ~(a - 1); }

extern "C" void kernel_launch(void* const* d_in, const int* in_sizes, int n_in,
                              void* d_out, int out_size, void* d_ws, size_t ws_size,
                              hipStream_t stream)
{
    const float* xin = (const float*)d_in[0];
    const int*   ei  = (const int*)d_in[1];
    const float* W1  = (const float*)d_in[2];
    const float* b1  = (const float*)d_in[3];
    const float* W2  = (const float*)d_in[4];
    const float* b2  = (const float*)d_in[5];
    const float* W3  = (const float*)d_in[6];
    const float* b3  = (const float*)d_in[7];
    float* out = (float*)d_out;

    const int N = in_sizes[0] / 256;   // 100000
    const int E = in_sizes[1] / 2;     // 1600000
    const int ROWS = 2 * N;            // 200000 (divisible by 64)

    char* ws = (char*)d_ws;
    size_t off = 0;
    _Float16* Xh = (_Float16*)(ws + off);   off = align_up(off + (size_t)ROWS * 128 * 2, 256);
    _Float16* Ah = (_Float16*)(ws + off);   off = align_up(off + (size_t)ROWS * 128 * 2, 256);
    _Float16* Wt1 = (_Float16*)(ws + off);  off = align_up(off + 16384 * 2, 256);
    _Float16* Wt2 = (_Float16*)(ws + off);  off = align_up(off + 16384 * 2, 256);
    _Float16* Wt3 = (_Float16*)(ws + off);  off = align_up(off + 16384 * 2, 256);
    int* cnt = (int*)(ws + off);            off = align_up(off + (size_t)N * 4, 256);
    int* row_start = (int*)(ws + off);      off = align_up(off + (size_t)(N + 1) * 4, 256);
    int* cursor = (int*)(ws + off);         off = align_up(off + (size_t)N * 4, 256);
    float* dinvp = (float*)(ws + off);      off = align_up(off + (size_t)N * 4, 256);
    int* bsum = (int*)(ws + off);           off = align_up(off + 1024 * 4, 256);
    int2* csr = (int2*)(ws + off);          off = align_up(off + (size_t)E * 8, 256);

    const int nb = (N + 1023) / 1024;

    // ---- input -> fp16; W -> fp16 transposed ----
    const int n4 = ROWS * 32;
    cvt_kernel<<<(n4 + 255) / 256, 256, 0, stream>>>(xin, Xh, n4);
    wt_kernel<<<64, 256, 0, stream>>>(W1, Wt1);
    wt_kernel<<<64, 256, 0, stream>>>(W2, Wt2);
    wt_kernel<<<64, 256, 0, stream>>>(W3, Wt3);

    // ---- build CSR ----
    hipMemsetAsync(cnt, 0, (size_t)N * 4, stream);
    deg_kernel<<<(E + 255) / 256, 256, 0, stream>>>(ei, cnt, E);
    scan_partials<<<nb, 256, 0, stream>>>(cnt, bsum, N);
    scan_bsums<<<1, 128, 0, stream>>>(bsum, nb);
    scan_final<<<nb, 256, 0, stream>>>(cnt, bsum, row_start, cursor, dinvp, N, E);
    fill_kernel<<<(E + 255) / 256, 256, 0, stream>>>(ei, dinvp, cursor, csr, E);

    const int agrid = (N + 3) / 4;
    const int ggrid = ROWS / 64;   // 3125, exact

    // layer 1
    agg_kernel<<<agrid, 256, 0, stream>>>(Xh, Ah, row_start, csr, dinvp, N);
    gemm_mfma<true><<<ggrid, 256, 0, stream>>>(Ah, Wt1, b1, Xh, ROWS);
    // layer 2
    agg_kernel<<<agrid, 256, 0, stream>>>(Xh, Ah, row_start, csr, dinvp, N);
    gemm_mfma<true><<<ggrid, 256, 0, stream>>>(Ah, Wt2, b2, Xh, ROWS);
    // layer 3
    agg_kernel<<<agrid, 256, 0, stream>>>(Xh, Ah, row_start, csr, dinvp, N);
    gemm_mfma<false><<<ggrid, 256, 0, stream>>>(Ah, Wt3, b3, out, ROWS);
}